// Round 2
// baseline (582.101 us; speedup 1.0000x reference)
//
#include <hip/hip_runtime.h>

// bf16 stored as raw ushort everywhere; MFMA consumes __bf16 vectors.
typedef unsigned short u16;
using bf16x8  = __attribute__((ext_vector_type(8))) __bf16;
using floatx4 = __attribute__((ext_vector_type(4))) float;

__device__ __forceinline__ u16 f2bf(float f) {
  unsigned int u = __builtin_bit_cast(unsigned int, f);
  u += 0x7fffu + ((u >> 16) & 1u);          // round-to-nearest-even
  return (u16)(u >> 16);
}

#define AS1(p) ((const __attribute__((address_space(1))) void*)(p))
#define AS3(p) ((__attribute__((address_space(3))) void*)(p))

// C = A * Bt^T (+bias) ; A:[M,K] bf16 row-major, Bt:[N,K] bf16 row-major.
// 128x128 block tile, 4 waves in 2x2, each wave 64x64 via 4x4 16x16x32 MFMAs.
// Staging: global_load_lds width 16, LDS tiles unpadded [128][32] (wave-uniform
// base + lane*16 constraint).
// out_mode: 0 = fp32 row-major [M,N]; 1 = bf16 row-major [M,N];
//           2 = bf16 transposed per-batch: C[b][col][s], b=row/trows, s=row%trows
__global__ __launch_bounds__(256) void gemm_bt(
    const u16* __restrict__ A, const u16* __restrict__ Bt,
    void* __restrict__ Cout, const float* __restrict__ bias,
    int N, int K, float alpha, int out_mode, int trows)
{
  __shared__ u16 As[128 * 32];
  __shared__ u16 Bs[128 * 32];
  const int tid  = threadIdx.x;
  const int wave = tid >> 6, lane = tid & 63;
  const int wm = (wave >> 1) * 64, wn = (wave & 1) * 64;
  const long bm = (long)blockIdx.y * 128, bn = (long)blockIdx.x * 128;

  floatx4 acc[4][4] = {};

  const int srow = lane >> 2;          // row within 16-row staging chunk
  const int scol = (lane & 3) * 8;     // bf16 col offset within 32-wide tile
  const u16* Ab = A + bm * K;
  const u16* Bb = Bt + bn * K;
  const int c0 = wave * 2, c1 = c0 + 1;
  const int fr = lane & 15;            // fragment row
  const int kq = (lane >> 4) * 8;      // fragment k-quad offset

  for (int k0 = 0; k0 < K; k0 += 32) {
    __syncthreads();   // previous iter's LDS reads complete
    __builtin_amdgcn_global_load_lds(AS1(Ab + (long)(c0*16 + srow)*K + k0 + scol), AS3(As + c0*512), 16, 0, 0);
    __builtin_amdgcn_global_load_lds(AS1(Ab + (long)(c1*16 + srow)*K + k0 + scol), AS3(As + c1*512), 16, 0, 0);
    __builtin_amdgcn_global_load_lds(AS1(Bb + (long)(c0*16 + srow)*K + k0 + scol), AS3(Bs + c0*512), 16, 0, 0);
    __builtin_amdgcn_global_load_lds(AS1(Bb + (long)(c1*16 + srow)*K + k0 + scol), AS3(Bs + c1*512), 16, 0, 0);
    __syncthreads();   // compiler drains vmcnt before barrier

    bf16x8 af[4], bfv[4];
#pragma unroll
    for (int mi = 0; mi < 4; ++mi)
      af[mi] = *(const bf16x8*)(As + (wm + mi*16 + fr)*32 + kq);
#pragma unroll
    for (int ni = 0; ni < 4; ++ni)
      bfv[ni] = *(const bf16x8*)(Bs + (wn + ni*16 + fr)*32 + kq);
#pragma unroll
    for (int mi = 0; mi < 4; ++mi)
#pragma unroll
      for (int ni = 0; ni < 4; ++ni)
        acc[mi][ni] = __builtin_amdgcn_mfma_f32_16x16x32_bf16(af[mi], bfv[ni], acc[mi][ni], 0, 0, 0);
  }

  // C/D layout: col = lane&15, row = (lane>>4)*4 + r   (m89-verified)
  const int orow = (lane >> 4) * 4;
  const int ocol = lane & 15;
#pragma unroll
  for (int ni = 0; ni < 4; ++ni) {
    long col = bn + wn + ni*16 + ocol;
    float bv = bias ? bias[col] : 0.0f;
#pragma unroll
    for (int mi = 0; mi < 4; ++mi) {
      long row = bm + wm + mi*16 + orow;   // rows row..row+3, never cross a trows boundary
      if (out_mode == 0) {
        float* C = (float*)Cout;
#pragma unroll
        for (int r = 0; r < 4; ++r)
          C[(row + r) * N + col] = acc[mi][ni][r] * alpha + bv;
      } else if (out_mode == 1) {
        u16* C = (u16*)Cout;
#pragma unroll
        for (int r = 0; r < 4; ++r)
          C[(row + r) * N + col] = f2bf(acc[mi][ni][r] * alpha + bv);
      } else {
        // transposed per-batch: C[b][col][s], s = row % trows
        u16* C = (u16*)Cout;
        long b_ = row / trows, s = row - b_ * trows;
        ushort4 o;
        o.x = f2bf(acc[mi][ni][0] * alpha + bv);
        o.y = f2bf(acc[mi][ni][1] * alpha + bv);
        o.z = f2bf(acc[mi][ni][2] * alpha + bv);
        o.w = f2bf(acc[mi][ni][3] * alpha + bv);
        *(ushort4*)(C + b_ * (long)N * trows + col * (long)trows + s) = o;
      }
    }
  }
}

__global__ __launch_bounds__(256) void cast_f32_to_bf16(
    const float* __restrict__ in, u16* __restrict__ out, int n4)
{
  int i = blockIdx.x * 256 + threadIdx.x;
  if (i >= n4) return;
  float4 f = ((const float4*)in)[i];
  ushort4 o;
  o.x = f2bf(f.x); o.y = f2bf(f.y); o.z = f2bf(f.z); o.w = f2bf(f.w);
  ((ushort4*)out)[i] = o;
}

// out[c][r] = (bf16)in[r][c]; in fp32 [rows][cols]
__global__ void transpose_cast_f32_bf16(
    const float* __restrict__ in, u16* __restrict__ out, int rows, int cols)
{
  __shared__ float tile[32][33];
  int bx = blockIdx.x * 32, by = blockIdx.y * 32;
  int tx = threadIdx.x, ty = threadIdx.y;
  for (int i = ty; i < 32; i += 8)
    tile[i][tx] = in[(long)(by + i) * cols + bx + tx];
  __syncthreads();
  for (int i = ty; i < 32; i += 8)
    out[(long)(bx + i) * rows + by + tx] = f2bf(tile[tx][i]);
}

// row softmax over n=4096 fp32 scores -> bf16 probs; one block per row
__global__ __launch_bounds__(256) void softmax_rows(
    const float* __restrict__ S, u16* __restrict__ P, int n)
{
  const long row = blockIdx.x;
  const float* s = S + row * n;
  u16* p = P + row * n;
  const int tid = threadIdx.x, wave = tid >> 6, lane = tid & 63;
  float v[16];
  float mx = -3.0e38f;
#pragma unroll
  for (int i = 0; i < 16; ++i) { v[i] = s[tid + (i << 8)]; mx = fmaxf(mx, v[i]); }
#pragma unroll
  for (int off = 1; off < 64; off <<= 1) mx = fmaxf(mx, __shfl_xor(mx, off));
  __shared__ float red[8];
  if (lane == 0) red[wave] = mx;
  __syncthreads();
  mx = fmaxf(fmaxf(red[0], red[1]), fmaxf(red[2], red[3]));
  float sum = 0.0f;
#pragma unroll
  for (int i = 0; i < 16; ++i) { v[i] = __expf(v[i] - mx); sum += v[i]; }
#pragma unroll
  for (int off = 1; off < 64; off <<= 1) sum += __shfl_xor(sum, off);
  if (lane == 0) red[4 + wave] = sum;
  __syncthreads();
  sum = red[4] + red[5] + red[6] + red[7];
  float inv = 1.0f / sum;
#pragma unroll
  for (int i = 0; i < 16; ++i) p[tid + (i << 8)] = f2bf(v[i] * inv);
}

extern "C" void kernel_launch(void* const* d_in, const int* in_sizes, int n_in,
                              void* d_out, int out_size, void* d_ws, size_t ws_size,
                              hipStream_t stream) {
  const float* x  = (const float*)d_in[0];
  const float* Wq = (const float*)d_in[1];
  const float* bq = (const float*)d_in[2];
  const float* Wk = (const float*)d_in[3];
  const float* bk = (const float*)d_in[4];
  const float* Wv = (const float*)d_in[5];
  const float* bv = (const float*)d_in[6];
  const float* Wo = (const float*)d_in[7];
  const float* bo = (const float*)d_in[8];
  float* out = (float*)d_out;

  const int B = 2, S = 4096, D = 1024;
  const long MS = (long)B * S;  // 8192
  const long MB = 1L << 20;

  // ---- workspace layout (fits ws_size; persistent part = 72 MiB) ----
  //  [0,16M)   qb   bf16 [8192,1024]
  //  [16,32M)  kb   bf16 [8192,1024]
  //  [32,48M)  vT   bf16 [B][1024][4096]   (written directly by V projection)
  //  [48,64M)  xb   bf16 [8192,1024]  -- aliased with ob (xb dead before PV)
  //  [64,72M)  WqT/WkT/WvT/WoT bf16 [1024,1024] each
  //  [72M,..)  scoresF fp32 [c][4096] ; attnB bf16 [c][4096]
  char* w = (char*)d_ws;
  u16* qb  = (u16*)(w);
  u16* kb  = (u16*)(w + 16 * MB);
  u16* vT  = (u16*)(w + 32 * MB);
  u16* xb  = (u16*)(w + 48 * MB);
  u16* ob  = xb;                       // alias: xb dead before ob written
  u16* WqT = (u16*)(w + 64 * MB);
  u16* WkT = WqT + 1024L * 1024;
  u16* WvT = WkT + 1024L * 1024;
  u16* WoT = WvT + 1024L * 1024;
  char* chunkBase = w + 72 * MB;

  // Q-chunk rows c: scores fp32 c*4096*4 + probs bf16 c*4096*2 = c*24576 B
  long avail = (long)ws_size - 72 * MB;
  long c = avail / 24576;
  if (c > 4096) c = 4096;
  c &= ~127L;                          // multiple of 128 (grid tiles)
  if (c < 128) c = 128;                // last resort; ws too small to matter
  float* scoresF = (float*)chunkBase;
  u16*   attnB   = (u16*)(chunkBase + c * 4096 * 4);

  // 1. cast x -> bf16
  cast_f32_to_bf16<<<dim3((unsigned)(MS * D / 4 / 256)), dim3(256), 0, stream>>>(
      x, xb, (int)(MS * D / 4));

  // 2. transpose+cast weights: WT[n][d] = W[d][n]
  dim3 tb(32, 8), tgW(32, 32);
  transpose_cast_f32_bf16<<<tgW, tb, 0, stream>>>(Wq, WqT, D, D);
  transpose_cast_f32_bf16<<<tgW, tb, 0, stream>>>(Wk, WkT, D, D);
  transpose_cast_f32_bf16<<<tgW, tb, 0, stream>>>(Wv, WvT, D, D);
  transpose_cast_f32_bf16<<<tgW, tb, 0, stream>>>(Wo, WoT, D, D);

  // 3. projections: q/k bf16 row-major; v written directly transposed per batch
  dim3 gp(D / 128, MS / 128);  // (8, 64)
  gemm_bt<<<gp, 256, 0, stream>>>(xb, WqT, qb, bq, D, D, 1.0f, 1, 0);
  gemm_bt<<<gp, 256, 0, stream>>>(xb, WkT, kb, bk, D, D, 1.0f, 1, 0);
  gemm_bt<<<gp, 256, 0, stream>>>(xb, WvT, vT, bv, D, D, 1.0f, 2, S);

  // 4. attention, chunked over Q rows to fit ws
  const float scale = 0.125f;  // 1/sqrt(64)
  const int nchunk = (int)(S / c);
  for (int b = 0; b < B; ++b) {
    const u16* qb_b = qb + (long)b * S * D;
    const u16* kb_b = kb + (long)b * S * D;
    const u16* vT_b = vT + (long)b * D * S;
    u16* ob_b = ob + (long)b * S * D;
    for (int qc = 0; qc < nchunk; ++qc) {
      const u16* qA = qb_b + (long)qc * c * D;
      gemm_bt<<<dim3(S / 128, (unsigned)(c / 128)), 256, 0, stream>>>(
          qA, kb_b, scoresF, nullptr, S, D, scale, 0, 0);
      softmax_rows<<<dim3((unsigned)c), 256, 0, stream>>>(scoresF, attnB, S);
      gemm_bt<<<dim3(D / 128, (unsigned)(c / 128)), 256, 0, stream>>>(
          attnB, vT_b, ob_b + (long)qc * c * D, nullptr, D, S, 1.0f, 1, 0);
    }
  }

  // 5. final projection -> fp32 d_out
  gemm_bt<<<gp, 256, 0, stream>>>(ob, WoT, out, bo, D, D, 1.0f, 0, 0);
}

// Round 3
// 521.959 us; speedup vs baseline: 1.1152x; 1.1152x over previous
//
#include <hip/hip_runtime.h>

// bf16 stored as raw ushort everywhere; MFMA consumes __bf16 vectors.
typedef unsigned short u16;
using bf16x8  = __attribute__((ext_vector_type(8))) __bf16;
using floatx4 = __attribute__((ext_vector_type(4))) float;

__device__ __forceinline__ u16 f2bf(float f) {
  unsigned int u = __builtin_bit_cast(unsigned int, f);
  u += 0x7fffu + ((u >> 16) & 1u);          // round-to-nearest-even
  return (u16)(u >> 16);
}

#define AS1(p) ((const __attribute__((address_space(1))) void*)(p))
#define AS3(p) ((__attribute__((address_space(3))) void*)(p))

// ---- shared GEMM core macros (m97 structure: 128x128 tile, 4 waves 2x2,
//      global_load_lds width16, LDS [128][32] unpadded) ----
#define GEMM_PROLOGUE()                                                      \
  __shared__ u16 As[128 * 32];                                               \
  __shared__ u16 Bs[128 * 32];                                               \
  const int tid  = threadIdx.x;                                              \
  const int wave = tid >> 6, lane = tid & 63;                                \
  const int wm = (wave >> 1) * 64, wn = (wave & 1) * 64;                     \
  const long bm = (long)blockIdx.y * 128, bn = (long)blockIdx.x * 128;       \
  floatx4 acc[4][4] = {};                                                    \
  const int srow = lane >> 2;                                                \
  const int scol = (lane & 3) * 8;                                           \
  const int c0 = wave * 2, c1 = c0 + 1;                                      \
  const int fr = lane & 15;                                                  \
  const int kq = (lane >> 4) * 8;

#define GEMM_KSTEP(Ab, Bb, K, k0)                                            \
  {                                                                          \
    __syncthreads();                                                         \
    __builtin_amdgcn_global_load_lds(AS1(Ab + (long)(c0*16 + srow)*K + k0 + scol), AS3(As + c0*512), 16, 0, 0); \
    __builtin_amdgcn_global_load_lds(AS1(Ab + (long)(c1*16 + srow)*K + k0 + scol), AS3(As + c1*512), 16, 0, 0); \
    __builtin_amdgcn_global_load_lds(AS1(Bb + (long)(c0*16 + srow)*K + k0 + scol), AS3(Bs + c0*512), 16, 0, 0); \
    __builtin_amdgcn_global_load_lds(AS1(Bb + (long)(c1*16 + srow)*K + k0 + scol), AS3(Bs + c1*512), 16, 0, 0); \
    __syncthreads();                                                         \
    bf16x8 af[4], bfv[4];                                                    \
    _Pragma("unroll")                                                        \
    for (int mi = 0; mi < 4; ++mi)                                           \
      af[mi] = *(const bf16x8*)(As + (wm + mi*16 + fr)*32 + kq);             \
    _Pragma("unroll")                                                        \
    for (int ni = 0; ni < 4; ++ni)                                           \
      bfv[ni] = *(const bf16x8*)(Bs + (wn + ni*16 + fr)*32 + kq);            \
    _Pragma("unroll")                                                        \
    for (int mi = 0; mi < 4; ++mi)                                           \
      _Pragma("unroll")                                                      \
      for (int ni = 0; ni < 4; ++ni)                                         \
        acc[mi][ni] = __builtin_amdgcn_mfma_f32_16x16x32_bf16(af[mi], bfv[ni], acc[mi][ni], 0, 0, 0); \
  }

// C = A * Bt^T (+bias); out_mode: 0 = fp32 row-major; 1 = bf16 row-major.
__global__ __launch_bounds__(256) void gemm_bt(
    const u16* __restrict__ A, const u16* __restrict__ Bt,
    void* __restrict__ Cout, const float* __restrict__ bias,
    int N, int K, float alpha, int out_mode)
{
  GEMM_PROLOGUE();
  const u16* Ab = A + bm * K;
  const u16* Bb = Bt + bn * K;
  for (int k0 = 0; k0 < K; k0 += 32) GEMM_KSTEP(Ab, Bb, K, k0);

  // C/D layout: col = lane&15, row = (lane>>4)*4 + r   (m89-verified)
  const int orow = (lane >> 4) * 4;
  const int ocol = lane & 15;
#pragma unroll
  for (int ni = 0; ni < 4; ++ni) {
    long col = bn + wn + ni*16 + ocol;
    float bv = bias ? bias[col] : 0.0f;
#pragma unroll
    for (int mi = 0; mi < 4; ++mi) {
      long row = bm + wm + mi*16 + orow;
      if (out_mode == 0) {
        float* C = (float*)Cout;
#pragma unroll
        for (int r = 0; r < 4; ++r)
          C[(row + r) * N + col] = acc[mi][ni][r] * alpha + bv;
      } else {
        u16* C = (u16*)Cout;
#pragma unroll
        for (int r = 0; r < 4; ++r)
          C[(row + r) * N + col] = f2bf(acc[mi][ni][r] * alpha + bv);
      }
    }
  }
}

// Fused QKV projection: A=xb [8192,1024], Bt=WqkvT [3072,1024], grid (24,64).
// cols [0,1024)->qb row-major; [1024,2048)->kb row-major;
// [2048,3072)->vT transposed per-batch (vT[b][d][s], S=4096 rows/batch).
__global__ __launch_bounds__(256) void gemm_qkv(
    const u16* __restrict__ A, const u16* __restrict__ Bt,
    u16* __restrict__ qb, u16* __restrict__ kb, u16* __restrict__ vT,
    const float* __restrict__ bq, const float* __restrict__ bk,
    const float* __restrict__ bv)
{
  const int K = 1024;
  GEMM_PROLOGUE();
  const u16* Ab = A + bm * K;
  const u16* Bb = Bt + bn * K;
  for (int k0 = 0; k0 < K; k0 += 32) GEMM_KSTEP(Ab, Bb, K, k0);

  const int orow = (lane >> 4) * 4;
  const int ocol = lane & 15;
#pragma unroll
  for (int ni = 0; ni < 4; ++ni) {
    long col = bn + wn + ni*16 + ocol;   // [0,3072)
    const float* bias = (col < 1024) ? bq : (col < 2048) ? bk : bv;
    float bvv = bias[col & 1023];
#pragma unroll
    for (int mi = 0; mi < 4; ++mi) {
      long row = bm + wm + mi*16 + orow;   // [0,8192)
      if (col < 2048) {
        u16* C = (col < 1024) ? qb : kb;
        long cc = col & 1023;
#pragma unroll
        for (int r = 0; r < 4; ++r)
          C[(row + r) * 1024 + cc] = f2bf(acc[mi][ni][r] + bvv);
      } else {
        long b_ = row >> 12, s = row & 4095, d = col - 2048;
        ushort4 o;
        o.x = f2bf(acc[mi][ni][0] + bvv);
        o.y = f2bf(acc[mi][ni][1] + bvv);
        o.z = f2bf(acc[mi][ni][2] + bvv);
        o.w = f2bf(acc[mi][ni][3] + bvv);
        *(ushort4*)(vT + b_ * (1024L * 4096) + d * 4096L + s) = o;
      }
    }
  }
}

// Split-K GEMM: z = blockIdx.z picks K-slice [z*Ks,(z+1)*Ks); fp32 partial out
// at part + z*partStride (row-major M x N).
__global__ __launch_bounds__(256) void gemm_bt_splitk(
    const u16* __restrict__ A, const u16* __restrict__ Bt,
    float* __restrict__ part, long partStride, int N, int K, int Ks)
{
  GEMM_PROLOGUE();
  const u16* Ab = A + bm * K;
  const u16* Bb = Bt + bn * K;
  const int kbeg = blockIdx.z * Ks, kend = kbeg + Ks;
  for (int k0 = kbeg; k0 < kend; k0 += 32) GEMM_KSTEP(Ab, Bb, K, k0);

  float* C = part + (long)blockIdx.z * partStride;
  const int orow = (lane >> 4) * 4;
  const int ocol = lane & 15;
#pragma unroll
  for (int ni = 0; ni < 4; ++ni) {
    long col = bn + wn + ni*16 + ocol;
#pragma unroll
    for (int mi = 0; mi < 4; ++mi) {
      long row = bm + wm + mi*16 + orow;
#pragma unroll
      for (int r = 0; r < 4; ++r)
        C[(row + r) * N + col] = acc[mi][ni][r];
    }
  }
}

// out[i] = bf16(part0[i]+part1[i]+part2[i]+part3[i]); float4-vectorized
__global__ __launch_bounds__(256) void reduce4_bf16(
    const float* __restrict__ part, long stride, u16* __restrict__ out, int n4)
{
  int i = blockIdx.x * 256 + threadIdx.x;
  if (i >= n4) return;
  const float4* p0 = (const float4*)part;
  const float4* p1 = (const float4*)(part + stride);
  const float4* p2 = (const float4*)(part + 2 * stride);
  const float4* p3 = (const float4*)(part + 3 * stride);
  float4 a = p0[i], b = p1[i], c = p2[i], d = p3[i];
  ushort4 o;
  o.x = f2bf(a.x + b.x + c.x + d.x);
  o.y = f2bf(a.y + b.y + c.y + d.y);
  o.z = f2bf(a.z + b.z + c.z + d.z);
  o.w = f2bf(a.w + b.w + c.w + d.w);
  ((ushort4*)out)[i] = o;
}

__global__ __launch_bounds__(256) void cast_f32_to_bf16(
    const float* __restrict__ in, u16* __restrict__ out, int n4)
{
  int i = blockIdx.x * 256 + threadIdx.x;
  if (i >= n4) return;
  float4 f = ((const float4*)in)[i];
  ushort4 o;
  o.x = f2bf(f.x); o.y = f2bf(f.y); o.z = f2bf(f.z); o.w = f2bf(f.w);
  ((ushort4*)out)[i] = o;
}

// out[c][r] = (bf16)in[r][c]; in fp32 [rows][cols]
__global__ void transpose_cast_f32_bf16(
    const float* __restrict__ in, u16* __restrict__ out, int rows, int cols)
{
  __shared__ float tile[32][33];
  int bx = blockIdx.x * 32, by = blockIdx.y * 32;
  int tx = threadIdx.x, ty = threadIdx.y;
  for (int i = ty; i < 32; i += 8)
    tile[i][tx] = in[(long)(by + i) * cols + bx + tx];
  __syncthreads();
  for (int i = ty; i < 32; i += 8)
    out[(long)(bx + i) * rows + by + tx] = f2bf(tile[tx][i]);
}

// row softmax over n=4096 fp32 scores -> bf16 probs; one block per row
__global__ __launch_bounds__(256) void softmax_rows(
    const float* __restrict__ S, u16* __restrict__ P, int n)
{
  const long row = blockIdx.x;
  const float* s = S + row * n;
  u16* p = P + row * n;
  const int tid = threadIdx.x, wave = tid >> 6, lane = tid & 63;
  float v[16];
  float mx = -3.0e38f;
#pragma unroll
  for (int i = 0; i < 16; ++i) { v[i] = s[tid + (i << 8)]; mx = fmaxf(mx, v[i]); }
#pragma unroll
  for (int off = 1; off < 64; off <<= 1) mx = fmaxf(mx, __shfl_xor(mx, off));
  __shared__ float red[8];
  if (lane == 0) red[wave] = mx;
  __syncthreads();
  mx = fmaxf(fmaxf(red[0], red[1]), fmaxf(red[2], red[3]));
  float sum = 0.0f;
#pragma unroll
  for (int i = 0; i < 16; ++i) { v[i] = __expf(v[i] - mx); sum += v[i]; }
#pragma unroll
  for (int off = 1; off < 64; off <<= 1) sum += __shfl_xor(sum, off);
  if (lane == 0) red[4 + wave] = sum;
  __syncthreads();
  sum = red[4] + red[5] + red[6] + red[7];
  float inv = 1.0f / sum;
#pragma unroll
  for (int i = 0; i < 16; ++i) p[tid + (i << 8)] = f2bf(v[i] * inv);
}

extern "C" void kernel_launch(void* const* d_in, const int* in_sizes, int n_in,
                              void* d_out, int out_size, void* d_ws, size_t ws_size,
                              hipStream_t stream) {
  const float* x  = (const float*)d_in[0];
  const float* Wq = (const float*)d_in[1];
  const float* bq = (const float*)d_in[2];
  const float* Wk = (const float*)d_in[3];
  const float* bk = (const float*)d_in[4];
  const float* Wv = (const float*)d_in[5];
  const float* bv = (const float*)d_in[6];
  const float* Wo = (const float*)d_in[7];
  const float* bo = (const float*)d_in[8];
  float* out = (float*)d_out;

  const int B = 2, S = 4096, D = 1024;
  const long MS = (long)B * S;  // 8192
  const long MB = 1L << 20;

  // ---- workspace layout (persistent 72 MiB; ws_size known >= 168 MiB) ----
  //  [0,16M)   qb   bf16 [8192,1024]
  //  [16,32M)  kb   bf16 [8192,1024]
  //  [32,48M)  vT   bf16 [B][1024][4096]  (written by fused QKV epilogue)
  //  [48,64M)  xb   bf16 [8192,1024]  -- aliased with ob (xb dead before PV)
  //  [64,72M)  WqkvT bf16 [3072,1024] (6M) + WoT bf16 [1024,1024] (2M)
  //  [72M,..)  scoresF fp32 [c][4096] (reused as PV split-K fp32 partials,
  //            c*1024*4 floats) ; attnB bf16 [c][4096]
  char* w = (char*)d_ws;
  u16* qb  = (u16*)(w);
  u16* kb  = (u16*)(w + 16 * MB);
  u16* vT  = (u16*)(w + 32 * MB);
  u16* xb  = (u16*)(w + 48 * MB);
  u16* ob  = xb;                       // alias: xb dead before ob written
  u16* WqkvT = (u16*)(w + 64 * MB);    // rows 0-1023 Wq^T, 1024-2047 Wk^T, 2048-3071 Wv^T
  u16* WoT = WqkvT + 3072L * 1024;
  char* chunkBase = w + 72 * MB;

  // Q-chunk rows c (power-of-two divisor of 4096):
  // scores fp32 c*4096*4 + probs bf16 c*4096*2 = c*24576 B
  long avail = (long)ws_size - 72 * MB;
  long c = 4096;
  while (c > 128 && c * 24576 > avail) c >>= 1;
  float* scoresF = (float*)chunkBase;              // also split-K partial buf
  u16*   attnB   = (u16*)(chunkBase + c * 4096 * 4);

  // 1. cast x -> bf16
  cast_f32_to_bf16<<<dim3((unsigned)(MS * D / 4 / 256)), dim3(256), 0, stream>>>(
      x, xb, (int)(MS * D / 4));

  // 2. transpose+cast weights
  dim3 tb(32, 8), tgW(32, 32);
  transpose_cast_f32_bf16<<<tgW, tb, 0, stream>>>(Wq, WqkvT, D, D);
  transpose_cast_f32_bf16<<<tgW, tb, 0, stream>>>(Wk, WqkvT + 1024L * 1024, D, D);
  transpose_cast_f32_bf16<<<tgW, tb, 0, stream>>>(Wv, WqkvT + 2048L * 1024, D, D);
  transpose_cast_f32_bf16<<<tgW, tb, 0, stream>>>(Wo, WoT, D, D);

  // 3. fused QKV projection: grid (24,64) = 1536 blocks = 6/CU
  gemm_qkv<<<dim3(3 * D / 128, MS / 128), 256, 0, stream>>>(
      xb, WqkvT, qb, kb, vT, bq, bk, bv);

  // 4. attention, chunked over Q rows
  const float scale = 0.125f;  // 1/sqrt(64)
  const int nchunk = (int)(S / c);
  const long partStride = c * 1024;    // floats per split-K partial
  for (int b = 0; b < B; ++b) {
    const u16* qb_b = qb + (long)b * S * D;
    const u16* kb_b = kb + (long)b * S * D;
    const u16* vT_b = vT + (long)b * D * S;
    u16* ob_b = ob + (long)b * S * D;
    for (int qc = 0; qc < nchunk; ++qc) {
      const u16* qA = qb_b + (long)qc * c * D;
      gemm_bt<<<dim3(S / 128, (unsigned)(c / 128)), 256, 0, stream>>>(
          qA, kb_b, scoresF, nullptr, S, D, scale, 0);
      softmax_rows<<<dim3((unsigned)c), 256, 0, stream>>>(scoresF, attnB, S);
      // PV split-K=4: grid (8, c/128, 4) -> 4 blocks/CU at c=4096
      gemm_bt_splitk<<<dim3(D / 128, (unsigned)(c / 128), 4), 256, 0, stream>>>(
          attnB, vT_b, scoresF, partStride, D, S, S / 4);
      reduce4_bf16<<<dim3((unsigned)(c * D / 4 / 256)), 256, 0, stream>>>(
          scoresF, partStride, ob_b + (long)qc * c * D, (int)(c * D / 4));
    }
  }

  // 5. final projection -> fp32 d_out
  gemm_bt<<<dim3(D / 128, MS / 128), 256, 0, stream>>>(ob, WoT, out, bo, D, D, 1.0f, 0);
}

// Round 4
// 495.403 us; speedup vs baseline: 1.1750x; 1.0536x over previous
//
#include <hip/hip_runtime.h>

// bf16 stored as raw ushort everywhere; MFMA consumes __bf16 vectors.
typedef unsigned short u16;
using bf16x8  = __attribute__((ext_vector_type(8))) __bf16;
using floatx4 = __attribute__((ext_vector_type(4))) float;

__device__ __forceinline__ u16 f2bf(float f) {
  unsigned int u = __builtin_bit_cast(unsigned int, f);
  u += 0x7fffu + ((u >> 16) & 1u);          // round-to-nearest-even
  return (u16)(u >> 16);
}

#define AS1(p) ((const __attribute__((address_space(1))) void*)(p))
#define AS3(p) ((__attribute__((address_space(3))) void*)(p))

// ---- shared GEMM core macros (m97 structure: 128x128 tile, 4 waves 2x2,
//      global_load_lds width16, LDS [128][32] unpadded) ----
#define GEMM_PROLOGUE()                                                      \
  __shared__ u16 As[128 * 32];                                               \
  __shared__ u16 Bs[128 * 32];                                               \
  const int tid  = threadIdx.x;                                              \
  const int wave = tid >> 6, lane = tid & 63;                                \
  const int wm = (wave >> 1) * 64, wn = (wave & 1) * 64;                     \
  const long bm = (long)blockIdx.y * 128, bn = (long)blockIdx.x * 128;       \
  floatx4 acc[4][4] = {};                                                    \
  const int srow = lane >> 2;                                                \
  const int scol = (lane & 3) * 8;                                           \
  const int c0 = wave * 2, c1 = c0 + 1;                                      \
  const int fr = lane & 15;                                                  \
  const int kq = (lane >> 4) * 8;

#define GEMM_KSTEP(Ab, Bb, K, k0)                                            \
  {                                                                          \
    __syncthreads();                                                         \
    __builtin_amdgcn_global_load_lds(AS1(Ab + (long)(c0*16 + srow)*K + k0 + scol), AS3(As + c0*512), 16, 0, 0); \
    __builtin_amdgcn_global_load_lds(AS1(Ab + (long)(c1*16 + srow)*K + k0 + scol), AS3(As + c1*512), 16, 0, 0); \
    __builtin_amdgcn_global_load_lds(AS1(Bb + (long)(c0*16 + srow)*K + k0 + scol), AS3(Bs + c0*512), 16, 0, 0); \
    __builtin_amdgcn_global_load_lds(AS1(Bb + (long)(c1*16 + srow)*K + k0 + scol), AS3(Bs + c1*512), 16, 0, 0); \
    __syncthreads();                                                         \
    bf16x8 af[4], bfv[4];                                                    \
    _Pragma("unroll")                                                        \
    for (int mi = 0; mi < 4; ++mi)                                           \
      af[mi] = *(const bf16x8*)(As + (wm + mi*16 + fr)*32 + kq);             \
    _Pragma("unroll")                                                        \
    for (int ni = 0; ni < 4; ++ni)                                           \
      bfv[ni] = *(const bf16x8*)(Bs + (wn + ni*16 + fr)*32 + kq);            \
    _Pragma("unroll")                                                        \
    for (int mi = 0; mi < 4; ++mi)                                           \
      _Pragma("unroll")                                                      \
      for (int ni = 0; ni < 4; ++ni)                                         \
        acc[mi][ni] = __builtin_amdgcn_mfma_f32_16x16x32_bf16(af[mi], bfv[ni], acc[mi][ni], 0, 0, 0); \
  }

// C = A * Bt^T (+bias); out_mode: 0 = fp32 row-major; 1 = bf16 row-major.
__global__ __launch_bounds__(256) void gemm_bt(
    const u16* __restrict__ A, const u16* __restrict__ Bt,
    void* __restrict__ Cout, const float* __restrict__ bias,
    int N, int K, float alpha, int out_mode)
{
  GEMM_PROLOGUE();
  const u16* Ab = A + bm * K;
  const u16* Bb = Bt + bn * K;
  for (int k0 = 0; k0 < K; k0 += 32) GEMM_KSTEP(Ab, Bb, K, k0);

  // C/D layout: col = lane&15, row = (lane>>4)*4 + r   (m89-verified)
  const int orow = (lane >> 4) * 4;
  const int ocol = lane & 15;
#pragma unroll
  for (int ni = 0; ni < 4; ++ni) {
    long col = bn + wn + ni*16 + ocol;
    float bv = bias ? bias[col] : 0.0f;
#pragma unroll
    for (int mi = 0; mi < 4; ++mi) {
      long row = bm + wm + mi*16 + orow;
      if (out_mode == 0) {
        float* C = (float*)Cout;
#pragma unroll
        for (int r = 0; r < 4; ++r)
          C[(row + r) * N + col] = acc[mi][ni][r] * alpha + bv;
      } else {
        u16* C = (u16*)Cout;
#pragma unroll
        for (int r = 0; r < 4; ++r)
          C[(row + r) * N + col] = f2bf(acc[mi][ni][r] * alpha + bv);
      }
    }
  }
}

// QK^T + unnormalized exp: P = exp(scale * q k^T) bf16 [4096][4096], plus
// per-row partial sums l_part[cg][4096] fp32, cg = blockIdx.x*2 + wn/64.
// No max-subtraction: |scores| <= ~20 << 88 (fp32 exp range), so exp(s) is
// safe and exp(s)/sum(exp(s)) is exactly softmax.
__global__ __launch_bounds__(256) void gemm_qk_exp(
    const u16* __restrict__ A, const u16* __restrict__ Bt,
    u16* __restrict__ P, float* __restrict__ lpart, int N, int K, float alpha)
{
  GEMM_PROLOGUE();
  const u16* Ab = A + bm * K;
  const u16* Bb = Bt + bn * K;
  for (int k0 = 0; k0 < K; k0 += 32) GEMM_KSTEP(Ab, Bb, K, k0);

  const int orow = (lane >> 4) * 4;
  const int ocol = lane & 15;
  float rowsum[4][4];   // [mi][reg]
#pragma unroll
  for (int mi = 0; mi < 4; ++mi)
#pragma unroll
    for (int r = 0; r < 4; ++r) rowsum[mi][r] = 0.0f;

#pragma unroll
  for (int ni = 0; ni < 4; ++ni) {
    long col = bn + wn + ni*16 + ocol;
#pragma unroll
    for (int mi = 0; mi < 4; ++mi) {
      long row = bm + wm + mi*16 + orow;
#pragma unroll
      for (int r = 0; r < 4; ++r) {
        float p = __expf(acc[mi][ni][r] * alpha);
        P[(row + r) * N + col] = f2bf(p);
        rowsum[mi][r] += p;
      }
    }
  }
  // reduce rowsum across the 16 lanes of each quad (row lives in one quad)
#pragma unroll
  for (int mi = 0; mi < 4; ++mi)
#pragma unroll
    for (int r = 0; r < 4; ++r) {
      float s = rowsum[mi][r];
      s += __shfl_xor(s, 1); s += __shfl_xor(s, 2);
      s += __shfl_xor(s, 4); s += __shfl_xor(s, 8);
      rowsum[mi][r] = s;
    }
  if (ocol == 0) {
    long cg = blockIdx.x * 2 + (wn >> 6);
#pragma unroll
    for (int mi = 0; mi < 4; ++mi)
#pragma unroll
      for (int r = 0; r < 4; ++r)
        lpart[cg * 4096 + bm + wm + mi*16 + orow + r] = rowsum[mi][r];
  }
}

// Fused QKV projection: A=xb [8192,1024], Bt=WqkvT [3072,1024], grid (24,64).
// cols [0,1024)->qb row-major; [1024,2048)->kb row-major;
// [2048,3072)->vT transposed per-batch (vT[b][d][s], S=4096 rows/batch).
__global__ __launch_bounds__(256) void gemm_qkv(
    const u16* __restrict__ A, const u16* __restrict__ Bt,
    u16* __restrict__ qb, u16* __restrict__ kb, u16* __restrict__ vT,
    const float* __restrict__ bq, const float* __restrict__ bk,
    const float* __restrict__ bv)
{
  const int K = 1024;
  GEMM_PROLOGUE();
  const u16* Ab = A + bm * K;
  const u16* Bb = Bt + bn * K;
  for (int k0 = 0; k0 < K; k0 += 32) GEMM_KSTEP(Ab, Bb, K, k0);

  const int orow = (lane >> 4) * 4;
  const int ocol = lane & 15;
#pragma unroll
  for (int ni = 0; ni < 4; ++ni) {
    long col = bn + wn + ni*16 + ocol;   // [0,3072)
    const float* bias = (col < 1024) ? bq : (col < 2048) ? bk : bv;
    float bvv = bias[col & 1023];
#pragma unroll
    for (int mi = 0; mi < 4; ++mi) {
      long row = bm + wm + mi*16 + orow;   // [0,8192)
      if (col < 2048) {
        u16* C = (col < 1024) ? qb : kb;
        long cc = col & 1023;
#pragma unroll
        for (int r = 0; r < 4; ++r)
          C[(row + r) * 1024 + cc] = f2bf(acc[mi][ni][r] + bvv);
      } else {
        long b_ = row >> 12, s = row & 4095, d = col - 2048;
        ushort4 o;
        o.x = f2bf(acc[mi][ni][0] + bvv);
        o.y = f2bf(acc[mi][ni][1] + bvv);
        o.z = f2bf(acc[mi][ni][2] + bvv);
        o.w = f2bf(acc[mi][ni][3] + bvv);
        *(ushort4*)(vT + b_ * (1024L * 4096) + d * 4096L + s) = o;
      }
    }
  }
}

// Split-K GEMM: z = blockIdx.z picks K-slice [z*Ks,(z+1)*Ks); fp32 partial out
// at part + z*partStride (row-major M x N).
__global__ __launch_bounds__(256) void gemm_bt_splitk(
    const u16* __restrict__ A, const u16* __restrict__ Bt,
    float* __restrict__ part, long partStride, int N, int K, int Ks)
{
  GEMM_PROLOGUE();
  const u16* Ab = A + bm * K;
  const u16* Bb = Bt + bn * K;
  const int kbeg = blockIdx.z * Ks, kend = kbeg + Ks;
  for (int k0 = kbeg; k0 < kend; k0 += 32) GEMM_KSTEP(Ab, Bb, K, k0);

  float* C = part + (long)blockIdx.z * partStride;
  const int orow = (lane >> 4) * 4;
  const int ocol = lane & 15;
#pragma unroll
  for (int ni = 0; ni < 4; ++ni) {
    long col = bn + wn + ni*16 + ocol;
#pragma unroll
    for (int mi = 0; mi < 4; ++mi) {
      long row = bm + wm + mi*16 + orow;
#pragma unroll
      for (int r = 0; r < 4; ++r)
        C[(row + r) * N + col] = acc[mi][ni][r];
    }
  }
}

// l[r] = sum_{cg<64} lpart[cg][r]
__global__ __launch_bounds__(256) void combine_l(
    const float* __restrict__ lpart, float* __restrict__ l, int rows)
{
  int r = blockIdx.x * 256 + threadIdx.x;
  if (r >= rows) return;
  float s = 0.0f;
#pragma unroll 8
  for (int cg = 0; cg < 64; ++cg) s += lpart[(long)cg * rows + r];
  l[r] = s;
}

// out[i] = bf16((p0+p1+p2+p3)[i] / l[row]); row = i*4/1024
__global__ __launch_bounds__(256) void reduce4_div(
    const float* __restrict__ part, long stride, const float* __restrict__ l,
    u16* __restrict__ out, int n4)
{
  int i = blockIdx.x * 256 + threadIdx.x;
  if (i >= n4) return;
  float inv = 1.0f / l[i >> 8];
  float4 a = ((const float4*)part)[i];
  float4 b = ((const float4*)(part + stride))[i];
  float4 c = ((const float4*)(part + 2 * stride))[i];
  float4 d = ((const float4*)(part + 3 * stride))[i];
  ushort4 o;
  o.x = f2bf((a.x + b.x + c.x + d.x) * inv);
  o.y = f2bf((a.y + b.y + c.y + d.y) * inv);
  o.z = f2bf((a.z + b.z + c.z + d.z) * inv);
  o.w = f2bf((a.w + b.w + c.w + d.w) * inv);
  ((ushort4*)out)[i] = o;
}

__global__ __launch_bounds__(256) void cast_f32_to_bf16(
    const float* __restrict__ in, u16* __restrict__ out, int n4)
{
  int i = blockIdx.x * 256 + threadIdx.x;
  if (i >= n4) return;
  float4 f = ((const float4*)in)[i];
  ushort4 o;
  o.x = f2bf(f.x); o.y = f2bf(f.y); o.z = f2bf(f.z); o.w = f2bf(f.w);
  ((ushort4*)out)[i] = o;
}

// z in [0,4): out_z[c][r] = (bf16)in_z[r][c], 1024x1024 each
__global__ void transpose_w4(
    const float* __restrict__ W0, const float* __restrict__ W1,
    const float* __restrict__ W2, const float* __restrict__ W3,
    u16* __restrict__ O0, u16* __restrict__ O1,
    u16* __restrict__ O2, u16* __restrict__ O3)
{
  __shared__ float tile[32][33];
  const int z = blockIdx.z;
  const float* in = (z == 0) ? W0 : (z == 1) ? W1 : (z == 2) ? W2 : W3;
  u16* out = (z == 0) ? O0 : (z == 1) ? O1 : (z == 2) ? O2 : O3;
  int bx = blockIdx.x * 32, by = blockIdx.y * 32;
  int tx = threadIdx.x, ty = threadIdx.y;
  for (int i = ty; i < 32; i += 8)
    tile[i][tx] = in[(long)(by + i) * 1024 + bx + tx];
  __syncthreads();
  for (int i = ty; i < 32; i += 8)
    out[(long)(bx + i) * 1024 + by + tx] = f2bf(tile[tx][i]);
}

extern "C" void kernel_launch(void* const* d_in, const int* in_sizes, int n_in,
                              void* d_out, int out_size, void* d_ws, size_t ws_size,
                              hipStream_t stream) {
  const float* x  = (const float*)d_in[0];
  const float* Wq = (const float*)d_in[1];
  const float* bq = (const float*)d_in[2];
  const float* Wk = (const float*)d_in[3];
  const float* bk = (const float*)d_in[4];
  const float* Wv = (const float*)d_in[5];
  const float* bv = (const float*)d_in[6];
  const float* Wo = (const float*)d_in[7];
  const float* bo = (const float*)d_in[8];
  float* out = (float*)d_out;

  const int B = 2, S = 4096, D = 1024;
  const long MS = (long)B * S;  // 8192
  const long MB = 1L << 20;

  // ---- workspace layout (top usage exactly 168 MiB; ws_size >= 168 MiB) ----
  //  [0,16M)    qb   bf16 [8192,1024]
  //  [16,32M)   kb   bf16 [8192,1024]
  //  [32,48M)   vT   bf16 [B][1024][4096]  (written by fused QKV epilogue)
  //  [48,64M)   xb   bf16 [8192,1024]  -- aliased with ob (xb dead before PV)
  //  [64,72M)   WqkvT bf16 [3072,1024] (6M) + WoT bf16 [1024,1024] (2M)
  //  [72,104M)  probs bf16 [4096][4096]  (per batch, unnormalized exp)
  //  [104,168M) PV split-K=4 fp32 partials [4][4096][1024]
  // d_out (32MB fp32, dead until final proj) hosts l_part (1M) + l (16K).
  char* w = (char*)d_ws;
  u16* qb  = (u16*)(w);
  u16* kb  = (u16*)(w + 16 * MB);
  u16* vT  = (u16*)(w + 32 * MB);
  u16* xb  = (u16*)(w + 48 * MB);
  u16* ob  = xb;                       // alias: xb dead before ob written
  u16* WqkvT = (u16*)(w + 64 * MB);
  u16* WoT = WqkvT + 3072L * 1024;
  u16* probs = (u16*)(w + 72 * MB);
  float* partials = (float*)(w + 104 * MB);
  float* lpart = (float*)d_out;                    // [64][4096] fp32 = 1MB
  float* lrow  = (float*)((char*)d_out + 2 * MB);  // [4096] fp32

  // 1. cast x -> bf16
  cast_f32_to_bf16<<<dim3((unsigned)(MS * D / 4 / 256)), dim3(256), 0, stream>>>(
      x, xb, (int)(MS * D / 4));

  // 2. transpose+cast all 4 weights in one launch
  transpose_w4<<<dim3(32, 32, 4), dim3(32, 8), 0, stream>>>(
      Wq, Wk, Wv, Wo, WqkvT, WqkvT + 1024L * 1024, WqkvT + 2048L * 1024, WoT);

  // 3. fused QKV projection: grid (24,64) = 1536 blocks
  gemm_qkv<<<dim3(3 * D / 128, MS / 128), 256, 0, stream>>>(
      xb, WqkvT, qb, kb, vT, bq, bk, bv);

  // 4. attention per batch: QK^T+exp -> combine l -> PV split-K=4 -> reduce/div
  const float scale = 0.125f;  // 1/sqrt(64)
  const long partStride = (long)S * D;   // 4096*1024 floats per split
  for (int b = 0; b < B; ++b) {
    const u16* qb_b = qb + (long)b * S * D;
    const u16* kb_b = kb + (long)b * S * D;
    const u16* vT_b = vT + (long)b * D * S;
    u16* ob_b = ob + (long)b * S * D;
    gemm_qk_exp<<<dim3(S / 128, S / 128), 256, 0, stream>>>(
        qb_b, kb_b, probs, lpart, S, D, scale);
    combine_l<<<dim3(S / 256), 256, 0, stream>>>(lpart, lrow, S);
    gemm_bt_splitk<<<dim3(D / 128, S / 128, 4), 256, 0, stream>>>(
        probs, vT_b, partials, partStride, D, S, S / 4);
    reduce4_div<<<dim3((unsigned)(S * D / 4 / 256)), 256, 0, stream>>>(
        partials, partStride, lrow, ob_b, (int)(S * D / 4));
  }

  // 5. final projection -> fp32 d_out (overwrites l_part/l scratch)
  gemm_bt<<<dim3(D / 128, MS / 128), 256, 0, stream>>>(ob, WoT, out, bo, D, D, 1.0f, 0);
}

// Round 5
// 431.594 us; speedup vs baseline: 1.3487x; 1.1478x over previous
//
#include <hip/hip_runtime.h>

// bf16 stored as raw ushort everywhere; MFMA consumes __bf16 vectors.
typedef unsigned short u16;
using bf16x8  = __attribute__((ext_vector_type(8))) __bf16;
using floatx4 = __attribute__((ext_vector_type(4))) float;

__device__ __forceinline__ u16 f2bf(float f) {
  unsigned int u = __builtin_bit_cast(unsigned int, f);
  u += 0x7fffu + ((u >> 16) & 1u);          // round-to-nearest-even
  return (u16)(u >> 16);
}

#define AS1(p) ((const __attribute__((address_space(1))) void*)(p))
#define AS3(p) ((__attribute__((address_space(3))) void*)(p))

// ---- GEMM core (m97 structure, BK=64 variant): 128x128 tile, 4 waves 2x2,
// global_load_lds width16, two BK=32 LDS buffers per matrix (identical
// per-buffer layout/banking to the verified m97 pattern), one barrier pair
// per 64 K => 32 MFMA per barrier (AITER-like MFMA:barrier ratio). ----
#define GEMM_PROLOGUE64()                                                    \
  __shared__ u16 As[2][128 * 32];                                            \
  __shared__ u16 Bs[2][128 * 32];                                            \
  const int tid  = threadIdx.x;                                              \
  const int wave = tid >> 6, lane = tid & 63;                                \
  const int wm = (wave >> 1) * 64, wn = (wave & 1) * 64;                     \
  const long bm = (long)blockIdx.y * 128, bn = (long)blockIdx.x * 128;       \
  floatx4 acc[4][4] = {};                                                    \
  const int srow = lane >> 2;                                                \
  const int scol = (lane & 3) * 8;                                           \
  const int c0 = wave * 2, c1 = c0 + 1;                                      \
  const int fr = lane & 15;                                                  \
  const int kq = (lane >> 4) * 8;

#define GEMM_KSTEP64(Ab, Bb, K, k0)                                          \
  {                                                                          \
    __syncthreads();                                                         \
    _Pragma("unroll")                                                        \
    for (int h = 0; h < 2; ++h) {                                            \
      const int kk = k0 + h * 32;                                            \
      __builtin_amdgcn_global_load_lds(AS1(Ab + (long)(c0*16 + srow)*K + kk + scol), AS3(As[h] + c0*512), 16, 0, 0); \
      __builtin_amdgcn_global_load_lds(AS1(Ab + (long)(c1*16 + srow)*K + kk + scol), AS3(As[h] + c1*512), 16, 0, 0); \
      __builtin_amdgcn_global_load_lds(AS1(Bb + (long)(c0*16 + srow)*K + kk + scol), AS3(Bs[h] + c0*512), 16, 0, 0); \
      __builtin_amdgcn_global_load_lds(AS1(Bb + (long)(c1*16 + srow)*K + kk + scol), AS3(Bs[h] + c1*512), 16, 0, 0); \
    }                                                                        \
    __syncthreads();                                                         \
    _Pragma("unroll")                                                        \
    for (int h = 0; h < 2; ++h) {                                            \
      bf16x8 af[4], bfv[4];                                                  \
      _Pragma("unroll")                                                      \
      for (int mi = 0; mi < 4; ++mi)                                         \
        af[mi] = *(const bf16x8*)(As[h] + (wm + mi*16 + fr)*32 + kq);        \
      _Pragma("unroll")                                                      \
      for (int ni = 0; ni < 4; ++ni)                                         \
        bfv[ni] = *(const bf16x8*)(Bs[h] + (wn + ni*16 + fr)*32 + kq);       \
      _Pragma("unroll")                                                      \
      for (int mi = 0; mi < 4; ++mi)                                         \
        _Pragma("unroll")                                                    \
        for (int ni = 0; ni < 4; ++ni)                                       \
          acc[mi][ni] = __builtin_amdgcn_mfma_f32_16x16x32_bf16(af[mi], bfv[ni], acc[mi][ni], 0, 0, 0); \
    }                                                                        \
  }

// C = A * Bt^T (+bias); out_mode: 0 = fp32 row-major; 1 = bf16 row-major.
__global__ __launch_bounds__(256) void gemm_bt(
    const u16* __restrict__ A, const u16* __restrict__ Bt,
    void* __restrict__ Cout, const float* __restrict__ bias,
    int N, int K, float alpha, int out_mode)
{
  GEMM_PROLOGUE64();
  const u16* Ab = A + bm * K;
  const u16* Bb = Bt + bn * K;
  for (int k0 = 0; k0 < K; k0 += 64) GEMM_KSTEP64(Ab, Bb, K, k0);

  // C/D layout: col = lane&15, row = (lane>>4)*4 + r   (m89-verified)
  const int orow = (lane >> 4) * 4;
  const int ocol = lane & 15;
#pragma unroll
  for (int ni = 0; ni < 4; ++ni) {
    long col = bn + wn + ni*16 + ocol;
    float bv = bias ? bias[col] : 0.0f;
#pragma unroll
    for (int mi = 0; mi < 4; ++mi) {
      long row = bm + wm + mi*16 + orow;
      if (out_mode == 0) {
        float* C = (float*)Cout;
#pragma unroll
        for (int r = 0; r < 4; ++r)
          C[(row + r) * N + col] = acc[mi][ni][r] * alpha + bv;
      } else {
        u16* C = (u16*)Cout;
#pragma unroll
        for (int r = 0; r < 4; ++r)
          C[(row + r) * N + col] = f2bf(acc[mi][ni][r] * alpha + bv);
      }
    }
  }
}

// QK^T + unnormalized exp: P = exp(scale * q k^T) bf16 [4096][4096], plus
// per-row partial sums l_part[cg][4096] fp32, cg = blockIdx.x*2 + wn/64.
// No max-subtraction: |scores| <= ~20 << 88 (fp32 exp range).
__global__ __launch_bounds__(256) void gemm_qk_exp(
    const u16* __restrict__ A, const u16* __restrict__ Bt,
    u16* __restrict__ P, float* __restrict__ lpart, int N, int K, float alpha)
{
  GEMM_PROLOGUE64();
  const u16* Ab = A + bm * K;
  const u16* Bb = Bt + bn * K;
  for (int k0 = 0; k0 < K; k0 += 64) GEMM_KSTEP64(Ab, Bb, K, k0);

  const int orow = (lane >> 4) * 4;
  const int ocol = lane & 15;
  float rowsum[4][4];   // [mi][reg]
#pragma unroll
  for (int mi = 0; mi < 4; ++mi)
#pragma unroll
    for (int r = 0; r < 4; ++r) rowsum[mi][r] = 0.0f;

#pragma unroll
  for (int ni = 0; ni < 4; ++ni) {
    long col = bn + wn + ni*16 + ocol;
#pragma unroll
    for (int mi = 0; mi < 4; ++mi) {
      long row = bm + wm + mi*16 + orow;
#pragma unroll
      for (int r = 0; r < 4; ++r) {
        float p = __expf(acc[mi][ni][r] * alpha);
        P[(row + r) * N + col] = f2bf(p);
        rowsum[mi][r] += p;
      }
    }
  }
  // reduce rowsum across the 16 lanes of each quad (row lives in one quad)
#pragma unroll
  for (int mi = 0; mi < 4; ++mi)
#pragma unroll
    for (int r = 0; r < 4; ++r) {
      float s = rowsum[mi][r];
      s += __shfl_xor(s, 1); s += __shfl_xor(s, 2);
      s += __shfl_xor(s, 4); s += __shfl_xor(s, 8);
      rowsum[mi][r] = s;
    }
  if (ocol == 0) {
    long cg = blockIdx.x * 2 + (wn >> 6);
#pragma unroll
    for (int mi = 0; mi < 4; ++mi)
#pragma unroll
      for (int r = 0; r < 4; ++r)
        lpart[cg * 4096 + bm + wm + mi*16 + orow + r] = rowsum[mi][r];
  }
}

// Fused QKV projection: A=xb [8192,1024], Bt=WqkvT [3072,1024], grid (24,64).
// cols [0,1024)->qb; [1024,2048)->kb; [2048,3072)->vT[b][d][s] transposed.
__global__ __launch_bounds__(256) void gemm_qkv(
    const u16* __restrict__ A, const u16* __restrict__ Bt,
    u16* __restrict__ qb, u16* __restrict__ kb, u16* __restrict__ vT,
    const float* __restrict__ bq, const float* __restrict__ bk,
    const float* __restrict__ bv)
{
  const int K = 1024;
  GEMM_PROLOGUE64();
  const u16* Ab = A + bm * K;
  const u16* Bb = Bt + bn * K;
  for (int k0 = 0; k0 < K; k0 += 64) GEMM_KSTEP64(Ab, Bb, K, k0);

  const int orow = (lane >> 4) * 4;
  const int ocol = lane & 15;
#pragma unroll
  for (int ni = 0; ni < 4; ++ni) {
    long col = bn + wn + ni*16 + ocol;   // [0,3072)
    const float* bias = (col < 1024) ? bq : (col < 2048) ? bk : bv;
    float bvv = bias[col & 1023];
#pragma unroll
    for (int mi = 0; mi < 4; ++mi) {
      long row = bm + wm + mi*16 + orow;   // [0,8192)
      if (col < 2048) {
        u16* C = (col < 1024) ? qb : kb;
        long cc = col & 1023;
#pragma unroll
        for (int r = 0; r < 4; ++r)
          C[(row + r) * 1024 + cc] = f2bf(acc[mi][ni][r] + bvv);
      } else {
        long b_ = row >> 12, s = row & 4095, d = col - 2048;
        ushort4 o;
        o.x = f2bf(acc[mi][ni][0] + bvv);
        o.y = f2bf(acc[mi][ni][1] + bvv);
        o.z = f2bf(acc[mi][ni][2] + bvv);
        o.w = f2bf(acc[mi][ni][3] + bvv);
        *(ushort4*)(vT + b_ * (1024L * 4096) + d * 4096L + s) = o;
      }
    }
  }
}

// Split-K GEMM: blockIdx.z picks K-slice [z*Ks,(z+1)*Ks); fp32 partial out.
__global__ __launch_bounds__(256) void gemm_bt_splitk(
    const u16* __restrict__ A, const u16* __restrict__ Bt,
    float* __restrict__ part, long partStride, int N, int K, int Ks)
{
  GEMM_PROLOGUE64();
  const u16* Ab = A + bm * K;
  const u16* Bb = Bt + bn * K;
  const int kbeg = blockIdx.z * Ks, kend = kbeg + Ks;
  for (int k0 = kbeg; k0 < kend; k0 += 64) GEMM_KSTEP64(Ab, Bb, K, k0);

  float* C = part + (long)blockIdx.z * partStride;
  const int orow = (lane >> 4) * 4;
  const int ocol = lane & 15;
#pragma unroll
  for (int ni = 0; ni < 4; ++ni) {
    long col = bn + wn + ni*16 + ocol;
#pragma unroll
    for (int mi = 0; mi < 4; ++mi) {
      long row = bm + wm + mi*16 + orow;
#pragma unroll
      for (int r = 0; r < 4; ++r)
        C[(row + r) * N + col] = acc[mi][ni][r];
    }
  }
}

// One block per output row (1024 cols): wave 0 sums the 64 lpart entries for
// this row (softmax denominator), broadcast; then out = (p0+p1)/l as bf16.
__global__ __launch_bounds__(256) void reduce2_div_row(
    const float* __restrict__ part, long stride,
    const float* __restrict__ lpart, u16* __restrict__ out)
{
  const int row = blockIdx.x;           // [0,4096)
  const int tid = threadIdx.x;
  __shared__ float sl;
  if (tid < 64) {
    float s = lpart[(long)tid * 4096 + row];
#pragma unroll
    for (int off = 32; off; off >>= 1) s += __shfl_down(s, off);
    if (tid == 0) sl = s;
  }
  __syncthreads();
  const float inv = 1.0f / sl;
  const long base = (long)row * 1024 + tid * 4;
  float4 a = *(const float4*)(part + base);
  float4 b = *(const float4*)(part + stride + base);
  ushort4 o;
  o.x = f2bf((a.x + b.x) * inv);
  o.y = f2bf((a.y + b.y) * inv);
  o.z = f2bf((a.z + b.z) * inv);
  o.w = f2bf((a.w + b.w) * inv);
  *(ushort4*)(out + base) = o;
}

__global__ __launch_bounds__(256) void cast_f32_to_bf16(
    const float* __restrict__ in, u16* __restrict__ out, int n4)
{
  int i = blockIdx.x * 256 + threadIdx.x;
  if (i >= n4) return;
  float4 f = ((const float4*)in)[i];
  ushort4 o;
  o.x = f2bf(f.x); o.y = f2bf(f.y); o.z = f2bf(f.z); o.w = f2bf(f.w);
  ((ushort4*)out)[i] = o;
}

// z in [0,4): out_z[c][r] = (bf16)in_z[r][c], 1024x1024 each
__global__ void transpose_w4(
    const float* __restrict__ W0, const float* __restrict__ W1,
    const float* __restrict__ W2, const float* __restrict__ W3,
    u16* __restrict__ O0, u16* __restrict__ O1,
    u16* __restrict__ O2, u16* __restrict__ O3)
{
  __shared__ float tile[32][33];
  const int z = blockIdx.z;
  const float* in = (z == 0) ? W0 : (z == 1) ? W1 : (z == 2) ? W2 : W3;
  u16* out = (z == 0) ? O0 : (z == 1) ? O1 : (z == 2) ? O2 : O3;
  int bx = blockIdx.x * 32, by = blockIdx.y * 32;
  int tx = threadIdx.x, ty = threadIdx.y;
  for (int i = ty; i < 32; i += 8)
    tile[i][tx] = in[(long)(by + i) * 1024 + bx + tx];
  __syncthreads();
  for (int i = ty; i < 32; i += 8)
    out[(long)(bx + i) * 1024 + by + tx] = f2bf(tile[tx][i]);
}

extern "C" void kernel_launch(void* const* d_in, const int* in_sizes, int n_in,
                              void* d_out, int out_size, void* d_ws, size_t ws_size,
                              hipStream_t stream) {
  const float* x  = (const float*)d_in[0];
  const float* Wq = (const float*)d_in[1];
  const float* bq = (const float*)d_in[2];
  const float* Wk = (const float*)d_in[3];
  const float* bk = (const float*)d_in[4];
  const float* Wv = (const float*)d_in[5];
  const float* bv = (const float*)d_in[6];
  const float* Wo = (const float*)d_in[7];
  const float* bo = (const float*)d_in[8];
  float* out = (float*)d_out;

  const int B = 2, S = 4096, D = 1024;
  const long MS = (long)B * S;  // 8192
  const long MB = 1L << 20;

  // ---- workspace layout (top usage 136 MiB; ws_size >= 168 MiB) ----
  //  [0,16M)    qb   bf16 [8192,1024]
  //  [16,32M)   kb   bf16 [8192,1024]
  //  [32,48M)   vT   bf16 [B][1024][4096]
  //  [48,64M)   xb   bf16 [8192,1024]  -- aliased with ob (xb dead before PV)
  //  [64,72M)   WqkvT bf16 [3072,1024] + WoT bf16 [1024,1024]
  //  [72,104M)  probs bf16 [4096][4096]  (per batch)
  //  [104,136M) PV split-K=2 fp32 partials [2][4096][1024]
  // d_out (32MB fp32, dead until final proj) hosts lpart [64][4096] fp32.
  char* w = (char*)d_ws;
  u16* qb  = (u16*)(w);
  u16* kb  = (u16*)(w + 16 * MB);
  u16* vT  = (u16*)(w + 32 * MB);
  u16* xb  = (u16*)(w + 48 * MB);
  u16* ob  = xb;                       // alias: xb dead before ob written
  u16* WqkvT = (u16*)(w + 64 * MB);
  u16* WoT = WqkvT + 3072L * 1024;
  u16* probs = (u16*)(w + 72 * MB);
  float* partials = (float*)(w + 104 * MB);
  float* lpart = (float*)d_out;        // [64][4096] fp32 = 1MB

  // 1. cast x -> bf16
  cast_f32_to_bf16<<<dim3((unsigned)(MS * D / 4 / 256)), dim3(256), 0, stream>>>(
      x, xb, (int)(MS * D / 4));

  // 2. transpose+cast all 4 weights in one launch
  transpose_w4<<<dim3(32, 32, 4), dim3(32, 8), 0, stream>>>(
      Wq, Wk, Wv, Wo, WqkvT, WqkvT + 1024L * 1024, WqkvT + 2048L * 1024, WoT);

  // 3. fused QKV projection: grid (24,64) = 1536 blocks
  gemm_qkv<<<dim3(3 * D / 128, MS / 128), 256, 0, stream>>>(
      xb, WqkvT, qb, kb, vT, bq, bk, bv);

  // 4. attention per batch: QK^T+exp -> PV split-K=2 -> fused reduce/div
  const float scale = 0.125f;  // 1/sqrt(64)
  const long partStride = (long)S * D;   // floats per split
  for (int b = 0; b < B; ++b) {
    const u16* qb_b = qb + (long)b * S * D;
    const u16* kb_b = kb + (long)b * S * D;
    const u16* vT_b = vT + (long)b * D * S;
    u16* ob_b = ob + (long)b * S * D;
    gemm_qk_exp<<<dim3(S / 128, S / 128), 256, 0, stream>>>(
        qb_b, kb_b, probs, lpart, S, D, scale);
    gemm_bt_splitk<<<dim3(D / 128, S / 128, 2), 256, 0, stream>>>(
        probs, vT_b, partials, partStride, D, S, S / 2);
    reduce2_div_row<<<dim3(S), 256, 0, stream>>>(
        partials, partStride, lpart, ob_b);
  }

  // 5. final projection -> fp32 d_out (overwrites lpart scratch)
  gemm_bt<<<dim3(D / 128, MS / 128), 256, 0, stream>>>(ob, WoT, out, bo, D, D, 1.0f, 0);
}